// Round 8
// baseline (547.433 us; speedup 1.0000x reference)
//
#include <hip/hip_runtime.h>
#include <hip/hip_fp16.h>
#include <cstdint>
#include <cstddef>

#define U_DIM 2048
#define D_DIM 2048
#define NH 16
#define DH 128
#define DFF 8192
#define EPS_RMS 1e-6f
#define ATTN_SCALE 0.088388347648318447f

typedef unsigned short u16;
typedef __attribute__((ext_vector_type(4))) float floatx4;
typedef __attribute__((ext_vector_type(8))) short shortx8;

__device__ __forceinline__ float bf2f(u16 u) {
  union { unsigned int i; float f; } v; v.i = ((unsigned int)u) << 16; return v.f;
}
__device__ __forceinline__ u16 f2bf(float f) {
  union { float f; unsigned int i; } v; v.f = f;
  return (u16)((v.i + 0x7fffu + ((v.i >> 16) & 1u)) >> 16);
}
__device__ __forceinline__ u16 f2h(float f) {
  __half h = __float2half_rn(f);
  union { __half h; u16 u; } c; c.h = h; return c.u;
}
__device__ __forceinline__ float h2f(u16 u) {
  union { __half h; u16 u; } c; c.u = u; return __half2float(c.h);
}

__device__ __forceinline__ void f2b_body(const float* __restrict__ in,
                                         u16* __restrict__ out, int i, int n4) {
  if (i >= n4) return;
  float4 f = reinterpret_cast<const float4*>(in)[i];
  ushort4 o;
  o.x = f2bf(f.x); o.y = f2bf(f.y); o.z = f2bf(f.z); o.w = f2bf(f.w);
  reinterpret_cast<ushort4*>(out)[i] = o;
}

// 4 fused D*D fp32->bf16 conversions (grid.y selects matrix)
__global__ __launch_bounds__(256) void k_f2b4(
    const float* __restrict__ s0, const float* __restrict__ s1,
    const float* __restrict__ s2, const float* __restrict__ s3,
    u16* __restrict__ d0, u16* __restrict__ d1,
    u16* __restrict__ d2, u16* __restrict__ d3, int n4) {
  const float* s; u16* d;
  switch (blockIdx.y) {
    case 0: s = s0; d = d0; break;
    case 1: s = s1; d = d1; break;
    case 2: s = s2; d = d2; break;
    default: s = s3; d = d3; break;
  }
  f2b_body(s, d, blockIdx.x * 256 + threadIdx.x, n4);
}

// 2 fused DFF*D fp32->bf16 conversions (w_up, w_down)
__global__ __launch_bounds__(256) void k_f2b2(
    const float* __restrict__ s0, const float* __restrict__ s1,
    u16* __restrict__ d0, u16* __restrict__ d1, int n4) {
  const float* s = blockIdx.y ? s1 : s0;
  u16* d = blockIdx.y ? d1 : d0;
  f2b_body(s, d, blockIdx.x * 256 + threadIdx.x, n4);
}

// Permute adj fp32 [U,U] into frag-major fp16 tiles:
// adjp[(qt*16+kt)*16384 + (c16*128 + row)*8 + j] = adj[qt*128+row][kt*128+c16+16*j]
__global__ __launch_bounds__(256) void k_prep_bias(const float* __restrict__ adj,
                                                   u16* __restrict__ adjp) {
  const int tile = blockIdx.x;           // qt*16 + kt
  const int qt = tile >> 4, kt = tile & 15;
  const int t = threadIdx.x;
  const int c16 = t & 15, rblk = t >> 4; // 16 row-groups of 8
  u16* outt = adjp + (size_t)tile * 16384;
#pragma unroll
  for (int rr = 0; rr < 8; rr++) {
    int r = rblk * 8 + rr;
    const float* src = adj + (size_t)(qt * 128 + r) * U_DIM + kt * 128 + c16;
    ushort4 o0, o1;
    o0.x = f2h(src[0]);    o0.y = f2h(src[16]);  o0.z = f2h(src[32]);  o0.w = f2h(src[48]);
    o1.x = f2h(src[64]);   o1.y = f2h(src[80]);  o1.z = f2h(src[96]);  o1.w = f2h(src[112]);
    ushort4* dst = reinterpret_cast<ushort4*>(outt + ((size_t)c16 * 128 + r) * 8);
    dst[0] = o0; dst[1] = o1;
  }
}

// out4 = X4 + sum of 4 bf16 partials (+ bias[col]); fp32 out
__global__ __launch_bounds__(256) void k_reduce4(
    const u16* __restrict__ p0, const u16* __restrict__ p1,
    const u16* __restrict__ p2, const u16* __restrict__ p3,
    const float* __restrict__ X, const float* __restrict__ bias,
    float* __restrict__ out, int n4) {
  int i = blockIdx.x * 256 + threadIdx.x;
  if (i >= n4) return;
  ushort4 a = reinterpret_cast<const ushort4*>(p0)[i];
  ushort4 b = reinterpret_cast<const ushort4*>(p1)[i];
  ushort4 c = reinterpret_cast<const ushort4*>(p2)[i];
  ushort4 d = reinterpret_cast<const ushort4*>(p3)[i];
  float4 xv = reinterpret_cast<const float4*>(X)[i];
  float4 r;
  r.x = xv.x + bf2f(a.x) + bf2f(b.x) + bf2f(c.x) + bf2f(d.x);
  r.y = xv.y + bf2f(a.y) + bf2f(b.y) + bf2f(c.y) + bf2f(d.y);
  r.z = xv.z + bf2f(a.z) + bf2f(b.z) + bf2f(c.z) + bf2f(d.z);
  r.w = xv.w + bf2f(a.w) + bf2f(b.w) + bf2f(c.w) + bf2f(d.w);
  if (bias) {
    int col = (i * 4) & (D_DIM - 1);
    float4 bv = *reinterpret_cast<const float4*>(bias + col);
    r.x += bv.x; r.y += bv.y; r.z += bv.z; r.w += bv.w;
  }
  reinterpret_cast<float4*>(out)[i] = r;
}

// fused: out = X + sum(4 partials); nrm = rmsnorm(out)*w  (one block per row)
__global__ __launch_bounds__(256) void k_reduce4norm(
    const u16* __restrict__ p0, const u16* __restrict__ p1,
    const u16* __restrict__ p2, const u16* __restrict__ p3,
    const float* __restrict__ X, const float* __restrict__ w,
    float* __restrict__ out, u16* __restrict__ nrm) {
  const int row = blockIdx.x;
  const int t = threadIdx.x;
  const size_t base = (size_t)row * 512;   // float4 units per row
  float4 r[2];
  float ss = 0.f;
#pragma unroll
  for (int h = 0; h < 2; h++) {
    size_t i = base + t + h * 256;
    ushort4 a = reinterpret_cast<const ushort4*>(p0)[i];
    ushort4 b = reinterpret_cast<const ushort4*>(p1)[i];
    ushort4 c = reinterpret_cast<const ushort4*>(p2)[i];
    ushort4 d = reinterpret_cast<const ushort4*>(p3)[i];
    float4 xv = reinterpret_cast<const float4*>(X)[i];
    float4 v;
    v.x = xv.x + bf2f(a.x) + bf2f(b.x) + bf2f(c.x) + bf2f(d.x);
    v.y = xv.y + bf2f(a.y) + bf2f(b.y) + bf2f(c.y) + bf2f(d.y);
    v.z = xv.z + bf2f(a.z) + bf2f(b.z) + bf2f(c.z) + bf2f(d.z);
    v.w = xv.w + bf2f(a.w) + bf2f(b.w) + bf2f(c.w) + bf2f(d.w);
    reinterpret_cast<float4*>(out)[i] = v;
    ss += v.x*v.x + v.y*v.y + v.z*v.z + v.w*v.w;
    r[h] = v;
  }
#pragma unroll
  for (int off = 32; off > 0; off >>= 1) ss += __shfl_xor(ss, off);
  __shared__ float red[4];
  if ((t & 63) == 0) red[t >> 6] = ss;
  __syncthreads();
  float tot = red[0] + red[1] + red[2] + red[3];
  float rms = rsqrtf(tot / (float)D_DIM + EPS_RMS);
  const float4* wr = reinterpret_cast<const float4*>(w);
#pragma unroll
  for (int h = 0; h < 2; h++) {
    float4 wv = wr[t + h * 256];
    ushort4 o;
    o.x = f2bf(r[h].x * rms * wv.x); o.y = f2bf(r[h].y * rms * wv.y);
    o.z = f2bf(r[h].z * rms * wv.z); o.w = f2bf(r[h].w * rms * wv.w);
    reinterpret_cast<ushort4*>(nrm)[base + t + h * 256] = o;
  }
}

// rmsnorm: one block per row of [U_DIM, D_DIM], fp32 in -> bf16 out
__global__ __launch_bounds__(256) void k_rmsnorm(const float* __restrict__ x,
                                                 const float* __restrict__ w,
                                                 u16* __restrict__ out) {
  const int row = blockIdx.x;
  const int t = threadIdx.x;
  const float4* xr = reinterpret_cast<const float4*>(x + (size_t)row * D_DIM);
  float4 a0 = xr[t], a1 = xr[t + 256];
  float ss = a0.x*a0.x + a0.y*a0.y + a0.z*a0.z + a0.w*a0.w
           + a1.x*a1.x + a1.y*a1.y + a1.z*a1.z + a1.w*a1.w;
#pragma unroll
  for (int off = 32; off > 0; off >>= 1) ss += __shfl_xor(ss, off);
  __shared__ float red[4];
  if ((t & 63) == 0) red[t >> 6] = ss;
  __syncthreads();
  float tot = red[0] + red[1] + red[2] + red[3];
  float r = rsqrtf(tot / (float)D_DIM + EPS_RMS);
  const float4* wr = reinterpret_cast<const float4*>(w);
  float4 w0 = wr[t], w1 = wr[t + 256];
  ushort4 o0, o1;
  o0.x = f2bf(a0.x * r * w0.x); o0.y = f2bf(a0.y * r * w0.y);
  o0.z = f2bf(a0.z * r * w0.z); o0.w = f2bf(a0.w * r * w0.w);
  o1.x = f2bf(a1.x * r * w1.x); o1.y = f2bf(a1.y * r * w1.y);
  o1.z = f2bf(a1.z * r * w1.z); o1.w = f2bf(a1.w * r * w1.w);
  ushort4* op = reinterpret_cast<ushort4*>(out + (size_t)row * D_DIM);
  op[t] = o0; op[t + 256] = o1;
}

__device__ __forceinline__ void async16(u16* lds, const u16* g) {
  __builtin_amdgcn_global_load_lds(
      (__attribute__((address_space(1))) void*)(g),
      (__attribute__((address_space(3))) void*)(lds), 16, 0, 0);
}

// ====== 256x256 GEMM core, 8-wave, half-tile counted-vmcnt pipeline =========
// Round-7 change (T4, m218/m201): round-6's loop drained vmcnt(0) at every
// K-tile top — the 8-DMA burst had only ~4 phases (~600 cyc) to cover ~900 cyc
// HBM latency, exposing the remainder each tile (MfmaUtil stuck at 35%).
// New schedule: K split into BKH=32 half-tiles; 4 half-buffers per matrix
// (same 128 KB LDS).  Each half-tile = 4 DMA issues (2 A + 2 B, 8 KB each).
// Keep 3 half-tiles (12 issues) in flight; before computing half h wait
// vmcnt(8) — retires exactly h's 4 oldest issues — NEVER 0 until the
// epilogue (8 -> 4 -> 0 over the last two halves).  Loads get ~6 phases to
// land and the pipe never empties.
// Hazards: staging h+3 targets buffer (h+3)&3 = (h-1)&3, whose ds_reads all
// retired via each wave's lgkmcnt(0) before the top-of-h barrier.  Per half:
// phase0 {ds_read A(mi0-3)+B(nj0-3); lgkm; 16 MFMA} barrier, phase1
// {ds_read A(mi4-7); lgkm; 16 MFMA}; top-of-next-half barrier closes the loop.
// Swizzle: byte-identical to the round-3-verified [rows][32] pattern
// (measured ZERO bank conflicts): slot (row,c) holds global chunk
// c ^ ((row>>1)&3); stage lane l sources chunk (l&3)^((l>>3)&3); read slot
// kq ^ ((fr>>1)&3) (row ≡ fr mod 16 and all other row terms ≡ 0 mod 8).
#define BKH 32

__device__ __forceinline__ void gemm256_core(
    const u16* __restrict__ A, int lda,
    const u16* __restrict__ B, int ldb,
    int K, int bm, int bn, u16* smem, floatx4 acc[8][4]) {
  const int t = threadIdx.x;
  const int wv = t >> 6, lane = t & 63;
  const int wm = wv >> 2, wn = wv & 3;
  const int fr = lane & 15, kq = lane >> 4;
  // staging: issue covers 128 rows (512 lanes x 16B = 8 KB, 64 B/row).
  // wave wv -> rows wv*16 + (lane>>2), slot chunk lane&3 (linear dest).
  const int srow = wv * 16 + (lane >> 2);
  const int scg  = (lane & 3) ^ ((lane >> 3) & 3);
  const u16* Ag = A + (size_t)(bm + srow) * lda + scg * 8;
  const u16* Bg = B + (size_t)(bn + srow) * ldb + scg * 8;
  u16* AsW = smem + wv * 512;            // wave-uniform base (+hb*8192, +r*4096)
  u16* BsW = smem + 32768 + wv * 512;
  // frag-read geometry
  const int ck   = (kq ^ ((fr >> 1) & 3)) * 8;
  const int arow = wm * 128 + fr;        // + mi*16
  const int brow = wn * 64 + fr;         // + ni*16
  const int nh = K / BKH;
  // prologue: stage halves 0..2 into bufs 0..2 (up to 12 issues in flight)
#pragma unroll
  for (int h0 = 0; h0 < 3; h0++) {
    if (h0 < nh) {
      const int hb = h0 * 8192;
      const size_t ko = (size_t)h0 * BKH;
      async16(AsW + hb,        Ag + ko);
      async16(AsW + hb + 4096, Ag + (size_t)128 * lda + ko);
      async16(BsW + hb,        Bg + ko);
      async16(BsW + hb + 4096, Bg + (size_t)128 * ldb + ko);
    }
  }
  for (int h = 0; h < nh; h++) {
    const int rem = nh - 1 - h;
    if (rem >= 2)      { asm volatile("s_waitcnt vmcnt(8)" ::: "memory"); }
    else if (rem == 1) { asm volatile("s_waitcnt vmcnt(4)" ::: "memory"); }
    else               { asm volatile("s_waitcnt vmcnt(0)" ::: "memory"); }
    __builtin_amdgcn_sched_barrier(0);
    __builtin_amdgcn_s_barrier();          // half h resident everywhere
    asm volatile("" ::: "memory");
    if (h + 3 < nh) {                      // stage h+3 into buffer (h+3)&3
      const int hb = ((h + 3) & 3) * 8192;
      const size_t ko = (size_t)(h + 3) * BKH;
      async16(AsW + hb,        Ag + ko);
      async16(AsW + hb + 4096, Ag + (size_t)128 * lda + ko);
      async16(BsW + hb,        Bg + ko);
      async16(BsW + hb + 4096, Bg + (size_t)128 * ldb + ko);
    }
    const u16* Ab = smem + (h & 3) * 8192;
    const u16* Bb = smem + 32768 + (h & 3) * 8192;
    shortx8 af[4], bf[4];
    // phase 0: A(mi 0-3) + B(nj 0-3), 16 MFMA
#pragma unroll
    for (int i = 0; i < 4; i++)
      af[i] = *reinterpret_cast<const shortx8*>(Ab + (arow + i * 16) * 32 + ck);
#pragma unroll
    for (int i = 0; i < 4; i++)
      bf[i] = *reinterpret_cast<const shortx8*>(Bb + (brow + i * 16) * 32 + ck);
    asm volatile("s_waitcnt lgkmcnt(0)" ::: "memory");
    __builtin_amdgcn_sched_barrier(0);
    __builtin_amdgcn_s_setprio(1);
#pragma unroll
    for (int i = 0; i < 4; i++)
#pragma unroll
      for (int j = 0; j < 4; j++)
        acc[i][j] = __builtin_amdgcn_mfma_f32_16x16x32_bf16(af[i], bf[j], acc[i][j], 0, 0, 0);
    __builtin_amdgcn_s_setprio(0);
    __builtin_amdgcn_s_barrier();
    asm volatile("" ::: "memory");
    // phase 1: A(mi 4-7), B reused, 16 MFMA
#pragma unroll
    for (int i = 0; i < 4; i++)
      af[i] = *reinterpret_cast<const shortx8*>(Ab + (arow + (i + 4) * 16) * 32 + ck);
    asm volatile("s_waitcnt lgkmcnt(0)" ::: "memory");
    __builtin_amdgcn_sched_barrier(0);
    __builtin_amdgcn_s_setprio(1);
#pragma unroll
    for (int i = 0; i < 4; i++)
#pragma unroll
      for (int j = 0; j < 4; j++)
        acc[i + 4][j] = __builtin_amdgcn_mfma_f32_16x16x32_bf16(af[i], bf[j], acc[i + 4][j], 0, 0, 0);
    __builtin_amdgcn_s_setprio(0);
  }
}

#define GEMM256_PRELUDE                                           \
  __shared__ u16 smem[65536]; /* 128 KB */                        \
  floatx4 acc[8][4];                                              \
  {                                                               \
    floatx4 zf = {0.f, 0.f, 0.f, 0.f};                            \
    for (int i = 0; i < 8; i++)                                   \
      for (int j = 0; j < 4; j++) acc[i][j] = zf;                 \
  }                                                               \
  const int bm = blockIdx.y * 256, bn = blockIdx.x * 256;

#define EPILOG256                                                 \
  const int lane_ = threadIdx.x & 63;                             \
  const int wv_ = threadIdx.x >> 6;                               \
  const int fr_ = lane_ & 15, kq_ = lane_ >> 4;                   \
  const int row0 = (wv_ >> 2) * 128 + kq_ * 4;                    \
  const int col0 = (wv_ & 3) * 64 + fr_;

__global__ __launch_bounds__(512, 1) void k_gemm_qkv(
    const u16* __restrict__ A, const u16* __restrict__ B,
    u16* __restrict__ Q, u16* __restrict__ Ko, u16* __restrict__ VT) {
  GEMM256_PRELUDE;
  gemm256_core(A, D_DIM, B, D_DIM, D_DIM, bm, bn, smem, acc);
  EPILOG256;
  if (bn < 4096) {
    u16* C = (bn < 2048) ? Q : Ko;
    const int cb = (bn < 2048) ? bn : bn - 2048;
#pragma unroll
    for (int mt = 0; mt < 8; mt++)
#pragma unroll
      for (int i = 0; i < 4; i++) {
        u16* cr = C + (size_t)(bm + row0 + mt*16 + i) * D_DIM + cb + col0;
#pragma unroll
        for (int nt = 0; nt < 4; nt++) cr[nt*16] = f2bf(acc[mt][nt][i]);
      }
  } else {
    const int cb = bn - 4096;
#pragma unroll
    for (int mt = 0; mt < 8; mt++)
#pragma unroll
      for (int nt = 0; nt < 4; nt++) {
        int col = cb + col0 + nt*16;
        int row = bm + row0 + mt*16;
        ushort4 o;
        o.x = f2bf(acc[mt][nt][0]); o.y = f2bf(acc[mt][nt][1]);
        o.z = f2bf(acc[mt][nt][2]); o.w = f2bf(acc[mt][nt][3]);
        *reinterpret_cast<ushort4*>(VT + (size_t)col * U_DIM + row) = o;
      }
  }
}

__global__ __launch_bounds__(512, 1) void k_gemm_splitk_part(
    const u16* __restrict__ A, int lda, const u16* __restrict__ B, int ldb,
    int Kc, u16* __restrict__ P, size_t pstride, int ldc) {
  GEMM256_PRELUDE;
  const int koff = blockIdx.z * Kc;
  gemm256_core(A + koff, lda, B + koff, ldb, Kc, bm, bn, smem, acc);
  u16* Pz = P + (size_t)blockIdx.z * pstride;
  EPILOG256;
#pragma unroll
  for (int mt = 0; mt < 8; mt++)
#pragma unroll
    for (int i = 0; i < 4; i++) {
      u16* cr = Pz + (size_t)(bm + row0 + mt*16 + i) * ldc + bn + col0;
#pragma unroll
      for (int nt = 0; nt < 4; nt++) cr[nt*16] = f2bf(acc[mt][nt][i]);
    }
}

__device__ __forceinline__ float fast_gelu(float v) {
  float u = v * (0.79788456080286536f + 0.035677408136300125f * v * v);
  float tt = fminf(fmaxf(2.f * u, -40.f), 40.f);
  float e = __expf(tt);
  return 0.5f * v * (1.f + (e - 1.f) / (e + 1.f));
}

__global__ __launch_bounds__(512, 1) void k_gemm_gelu(
    const u16* __restrict__ A, int lda, const u16* __restrict__ B, int ldb,
    int K, const float* __restrict__ bias, u16* __restrict__ C, int ldc) {
  GEMM256_PRELUDE;
  gemm256_core(A, lda, B, ldb, K, bm, bn, smem, acc);
  EPILOG256;
#pragma unroll
  for (int mt = 0; mt < 8; mt++)
#pragma unroll
    for (int i = 0; i < 4; i++) {
      size_t off = (size_t)(bm + row0 + mt*16 + i) * ldc + bn + col0;
#pragma unroll
      for (int nt = 0; nt < 4; nt++) {
        float v = acc[mt][nt][i] + bias[bn + col0 + nt*16];
        C[off + nt*16] = f2bf(fast_gelu(v));
      }
    }
}

// ---------------- Flash attention, KVBLK=64 (verified round 7) --------------
__global__ __launch_bounds__(256) void k_flash(
    const u16* __restrict__ Q, const u16* __restrict__ K,
    const u16* __restrict__ VT, const u16* __restrict__ ADJP,
    u16* __restrict__ O) {
  __shared__ u16 smem[36864];  // 72 KB
  const int qt = blockIdx.x, gh = blockIdx.y;   // qt in [0,32)
  const int t = threadIdx.x, wv = t >> 6, lane = t & 63;
  const int fr = lane & 15, kq = lane >> 4;
  const int c4 = lane & 3, r4 = lane >> 2;

  const u16* gq = Q + (size_t)(qt * 64) * D_DIM + gh * DH;
  const u16* gk = K + gh * DH;
  const u16* gv = VT + (size_t)(gh * DH) * U_DIM;

  // stage Q [64][128] rot16 into smem[0..8192)
#pragma unroll
  for (int it = 0; it < 4; it++) {
    int row = wv * 16 + it * 4 + kq;
    int cg = (fr + row) & 15;
    async16(smem + row * 128 + fr * 8, gq + (size_t)row * D_DIM + cg * 8);
  }
  __builtin_amdgcn_s_waitcnt(0);
  __syncthreads();
  shortx8 qf[4];
#pragma unroll
  for (int ks = 0; ks < 4; ks++) {
    int row = wv * 16 + fr;
    int slot = ((ks * 4 + kq) - row) & 15;
    qf[ks] = *reinterpret_cast<const shortx8*>(smem + row * 128 + slot * 8);
  }
  __syncthreads();  // Q reads done; smem reusable

  floatx4 oacc[8];
  float lrow[4];
#pragma unroll
  for (int nt = 0; nt < 8; nt++) { floatx4 z = {0.f,0.f,0.f,0.f}; oacc[nt] = z; }
#pragma unroll
  for (int i = 0; i < 4; i++) lrow[i] = 0.f;

  // stage K/V 64-key tile 0 into buffer 0
  {
    u16* Ks = smem; u16* Vs = smem + 16384;
#pragma unroll
    for (int it = 0; it < 4; it++) {            // K: 64 rows rot16
      int row = wv * 16 + it * 4 + kq;
      int cg = (fr + row) & 15;
      async16(Ks + row * 128 + fr * 8, gk + (size_t)row * D_DIM + cg * 8);
    }
#pragma unroll
    for (int sub = 0; sub < 2; sub++)           // V: 2 sub-blocks [128][32]
#pragma unroll
      for (int it = 0; it < 2; it++) {
        int row = wv * 32 + it * 16 + r4;
        int cg = (c4 + (row >> 1)) & 3;
        async16(Vs + sub * 4096 + row * 32 + c4 * 8,
                gv + (size_t)row * U_DIM + sub * 32 + cg * 8);
      }
  }

  u16* Pb = smem + 32768;
  for (int kt64 = 0; kt64 < 32; kt64++) {
    const int cur = kt64 & 1;
    u16* Ks = smem + cur * 8192;
    u16* Vs = smem + 16384 + cur * 8192;
    asm volatile("s_waitcnt vmcnt(0)" ::: "memory");
    __builtin_amdgcn_s_barrier();        // B1: buf[cur] DMA complete everywhere
    asm volatile("" ::: "memory");
    if (kt64 < 31) {   // prefetch buf[1-cur]; stays in flight to next B1
      u16* Kn = smem + (1 - cur) * 8192;
      u16* Vn = smem + 16384 + (1 - cur) * 8192;
      const u16* gkn = gk + (size_t)((kt64 + 1) * 64) * D_DIM;
      const u16* gvn = gv + (kt64 + 1) * 64;
#pragma unroll
      for (int it = 0; it < 4; it++) {
        int row = wv * 16 + it * 4 + kq;
        int cg = (fr + row) & 15;
        async16(Kn + row * 128 + fr * 8, gkn + (size_t)row * D_DIM + cg * 8);
      }
#pragma unroll
      for (int sub = 0; sub < 2; sub++)
#pragma unroll
        for (int it = 0; it < 2; it++) {
          int row = wv * 32 + it * 16 + r4;
          int cg = (c4 + (row >> 1)) & 3;
          async16(Vn + sub * 4096 + row * 32 + c4 * 8,
                  gvn + (size_t)row * U_DIM + sub * 32 + cg * 8);
        }
    }

    // S = Q K^T (64 keys -> 4 column groups: fr, 16+fr, 32+fr, 48+fr)
    floatx4 sacc[4];
    { floatx4 z = {0.f,0.f,0.f,0.f}; sacc[0]=z; sacc[1]=z; sacc[2]=z; sacc[3]=z; }
#pragma unroll
    for (int ks = 0; ks < 4; ks++) {
      int slotA = ((ks * 4 + kq) - fr) & 15;
      int slotB = ((ks * 4 + kq) - (16 + fr)) & 15;
      shortx8 kf0 = *reinterpret_cast<const shortx8*>(Ks + fr * 128 + slotA * 8);
      shortx8 kf1 = *reinterpret_cast<const shortx8*>(Ks + (16 + fr) * 128 + slotB * 8);
      shortx8 kf2 = *reinterpret_cast<const shortx8*>(Ks + (32 + fr) * 128 + slotA * 8);
      shortx8 kf3 = *reinterpret_cast<const shortx8*>(Ks + (48 + fr) * 128 + slotB * 8);
      sacc[0] = __builtin_amdgcn_mfma_f32_16x16x32_bf16(qf[ks], kf0, sacc[0], 0, 0, 0);
      sacc[1] = __builtin_amdgcn_mfma_f32_16x16x32_bf16(qf[ks], kf1, sacc[1], 0, 0, 0);
      sacc[2] = __builtin_amdgcn_mfma_f32_16x16x32_bf16(qf[ks], kf2, sacc[2], 0, 0, 0);
      sacc[3] = __builtin_amdgcn_mfma_f32_16x16x32_bf16(qf[ks], kf3, sacc[3], 0, 0, 0);
    }

    // fixed-shift softmax numerators; Pb row stride 64, sub-block = col>>5
    const u16* bt = ADJP + ((size_t)(qt >> 1) * 16 + (kt64 >> 1)) * 16384 + (kt64 & 1) * 4;
#pragma unroll
    for (int i = 0; i < 4; i++) {
      int rl = wv * 16 + kq * 4 + i;
      int r128 = (qt & 1) * 64 + rl;
      ushort4 bh = *reinterpret_cast<const ushort4*>(bt + ((size_t)fr * 128 + r128) * 8);
      float s0 = sacc[0][i] * ATTN_SCALE + h2f(bh.x);
      float s1 = sacc[1][i] * ATTN_SCALE + h2f(bh.y);
      float s2 = sacc[2][i] * ATTN_SCALE + h2f(bh.z);
      float s3 = sacc[3][i] * ATTN_SCALE + h2f(bh.w);
      float p0 = __expf(fminf(s0, 80.f));
      float p1 = __expf(fminf(s1, 80.f));
      float p2 = __expf(fminf(s2, 80.f));
      float p3 = __expf(fminf(s3, 80.f));
      int slot0 = ((fr >> 3) - (rl >> 1)) & 3;
      int slot1 = (((16 + fr) >> 3) - (rl >> 1)) & 3;
      Pb[rl * 64 + slot0 * 8 + (fr & 7)] = f2bf(p0);
      Pb[rl * 64 + slot1 * 8 + (fr & 7)] = f2bf(p1);
      Pb[rl * 64 + 32 + slot0 * 8 + (fr & 7)] = f2bf(p2);
      Pb[rl * 64 + 32 + slot1 * 8 + (fr & 7)] = f2bf(p3);
      lrow[i] += (p0 + p1) + (p2 + p3);
    }
    asm volatile("s_waitcnt lgkmcnt(0)" ::: "memory");
    __builtin_amdgcn_s_barrier();        // B2: Pb visible; prefetch in flight
    asm volatile("" ::: "memory");

    // O += P V   (k = 64 -> two MFMA k-steps per nt)
    shortx8 pf0, pf1;
    {
      int row = wv * 16 + fr;
      int slot = (kq - (row >> 1)) & 3;
      pf0 = *reinterpret_cast<const shortx8*>(Pb + row * 64 + slot * 8);
      pf1 = *reinterpret_cast<const shortx8*>(Pb + row * 64 + 32 + slot * 8);
    }
#pragma unroll
    for (int nt = 0; nt < 8; nt++) {
      int row = nt * 16 + fr;
      int slot = (kq - (row >> 1)) & 3;
      shortx8 vf0 = *reinterpret_cast<const shortx8*>(Vs + row * 32 + slot * 8);
      shortx8 vf1 = *reinterpret_cast<const shortx8*>(Vs + 4096 + row * 32 + slot * 8);
      oacc[nt] = __builtin_amdgcn_mfma_f32_16x16x32_bf16(pf0, vf0, oacc[nt], 0, 0, 0);
      oacc[nt] = __builtin_amdgcn_mfma_f32_16x16x32_bf16(pf1, vf1, oacc[nt], 0, 0, 0);
    }
    // (next-iter B1 orders Pb/Vs reads vs writes)
  }

  // epilogue: one cross-lane l-reduce per row, normalize, store bf16
#pragma unroll
  for (int i = 0; i < 4; i++) {
    int rl = wv * 16 + kq * 4 + i;
    float l = lrow[i];
    l += __shfl_xor(l, 1);
    l += __shfl_xor(l, 2);
    l += __shfl_xor(l, 4);
    l += __shfl_xor(l, 8);
    float inv = 1.f / l;
    u16* orow = O + (size_t)(qt * 64 + rl) * D_DIM + gh * DH + fr;
#pragma unroll
    for (int nt = 0; nt < 8; nt++)
      orow[nt * 16] = f2bf(oacc[nt][i] * inv);
  }
}

// Workspace timeline (MB offsets, peak 104):
//  A: hb@0-8, wob@48-56, wqkv@56-80, adjp@32-40 (prep)
//  B: qkv -> qb@8-16 kb@16-24 vtb@24-32
//  C: flash -> aob@40-48  (reads qb,kb,vtb,adjp)
//  D: out-proj partials opp@8-40 (qb/kb/vtb/adjp dead); reduce4norm -> out, h2b
//  E: wub@8-40 (opp dead), wdb@72-104 (wqkv dead) [one fused f2b2 launch];
//     ffb@40-72 (aob/wob dead); down partials dpp@8-40 (wub dead after gelu);
//     reduce -> out += sum + b_down
extern "C" void kernel_launch(void* const* d_in, const int* in_sizes, int n_in,
                              void* d_out, int out_size, void* d_ws, size_t ws_size,
                              hipStream_t stream) {
  (void)in_sizes; (void)n_in; (void)out_size; (void)ws_size;
  const float* x      = (const float*)d_in[0];
  const float* adj    = (const float*)d_in[1];
  const float* n1w    = (const float*)d_in[2];
  const float* n2w    = (const float*)d_in[3];
  const float* wq     = (const float*)d_in[4];
  const float* wk     = (const float*)d_in[5];
  const float* wv     = (const float*)d_in[6];
  const float* wo     = (const float*)d_in[7];
  const float* w_up   = (const float*)d_in[8];
  const float* b_up   = (const float*)d_in[9];
  const float* w_down = (const float*)d_in[10];
  const float* b_down = (const float*)d_in[11];
  float* out = (float*)d_out;
  char* ws = (char*)d_ws;
  const size_t MB = 1u << 20;
  u16* hb   = (u16*)(ws + 0*MB);
  u16* qb   = (u16*)(ws + 8*MB);
  u16* kb   = (u16*)(ws + 16*MB);
  u16* vtb  = (u16*)(ws + 24*MB);
  u16* adjp = (u16*)(ws + 32*MB);
  u16* aob  = (u16*)(ws + 40*MB);
  u16* wob  = (u16*)(ws + 48*MB);
  u16* wqkv = (u16*)(ws + 56*MB);
  u16* opp  = (u16*)(ws + 8*MB);   // 4 x 8MB out-proj partials
  u16* h2b  = (u16*)(ws + 0*MB);
  u16* wub  = (u16*)(ws + 8*MB);
  u16* ffb  = (u16*)(ws + 40*MB);
  u16* wdb  = (u16*)(ws + 72*MB);
  u16* dpp  = (u16*)(ws + 8*MB);   // 4 x 8MB FFN-down partials (overlays wub)

  dim3 blk(256);
  dim3 blk512(512);
  const int n4d = (D_DIM * D_DIM) / 4;
  const int n4f = (DFF * D_DIM) / 4;
  const size_t szd = (size_t)D_DIM * D_DIM;

  // phase A: fused weight conversion + bias permute + norm1
  k_f2b4<<<dim3((n4d + 255) / 256, 4), blk, 0, stream>>>(
      wq, wk, wv, wo, wqkv, wqkv + szd, wqkv + 2*szd, wob, n4d);
  k_prep_bias<<<256, blk, 0, stream>>>(adj, adjp);
  k_rmsnorm<<<U_DIM, blk, 0, stream>>>(x, n1w, hb);

  // phase B: fused QKV (256^2 tiles: 24 x 8 = 192 blocks)
  k_gemm_qkv<<<dim3(24, 8), blk512, 0, stream>>>(hb, wqkv, qb, kb, vtb);

  // phase C: flash attention (512 blocks, KVBLK=64) -> aob
  k_flash<<<dim3(32, 16), blk, 0, stream>>>(qb, kb, vtb, adjp, aob);

  // phase D: out-projection split-K4; fused reduce+residual+rmsnorm2
  k_gemm_splitk_part<<<dim3(8, 8, 4), blk512, 0, stream>>>(
      aob, D_DIM, wob, D_DIM, D_DIM/4, opp, szd, D_DIM);
  k_reduce4norm<<<U_DIM, blk, 0, stream>>>(
      opp, opp + szd, opp + 2*szd, opp + 3*szd, x, n2w, out, h2b);

  // phase E: FFN (fused w_up+w_down conversion in one launch)
  k_f2b2<<<dim3((n4f + 255) / 256, 2), blk, 0, stream>>>(w_up, w_down, wub, wdb, n4f);
  k_gemm_gelu<<<dim3(32, 8), blk512, 0, stream>>>(h2b, D_DIM, wub, D_DIM, D_DIM,
                                                  b_up, ffb, DFF);
  k_gemm_splitk_part<<<dim3(8, 8, 4), blk512, 0, stream>>>(
      ffb, DFF, wdb, DFF, DFF/4, dpp, szd, D_DIM);
  k_reduce4<<<(n4d + 255) / 256, blk, 0, stream>>>(
      dpp, dpp + szd, dpp + 2*szd, dpp + 3*szd, out, b_down, out, n4d);
}

// Round 9
// 532.654 us; speedup vs baseline: 1.0277x; 1.0277x over previous
//
#include <hip/hip_runtime.h>
#include <hip/hip_fp16.h>
#include <cstdint>
#include <cstddef>

#define U_DIM 2048
#define D_DIM 2048
#define NH 16
#define DH 128
#define DFF 8192
#define EPS_RMS 1e-6f
#define ATTN_SCALE 0.088388347648318447f

typedef unsigned short u16;
typedef __attribute__((ext_vector_type(4))) float floatx4;
typedef __attribute__((ext_vector_type(8))) short shortx8;

__device__ __forceinline__ float bf2f(u16 u) {
  union { unsigned int i; float f; } v; v.i = ((unsigned int)u) << 16; return v.f;
}
__device__ __forceinline__ u16 f2bf(float f) {
  union { float f; unsigned int i; } v; v.f = f;
  return (u16)((v.i + 0x7fffu + ((v.i >> 16) & 1u)) >> 16);
}
__device__ __forceinline__ u16 f2h(float f) {
  __half h = __float2half_rn(f);
  union { __half h; u16 u; } c; c.h = h; return c.u;
}
__device__ __forceinline__ float h2f(u16 u) {
  union { __half h; u16 u; } c; c.u = u; return __half2float(c.h);
}

__device__ __forceinline__ void f2b_body(const float* __restrict__ in,
                                         u16* __restrict__ out, int i, int n4) {
  if (i >= n4) return;
  float4 f = reinterpret_cast<const float4*>(in)[i];
  ushort4 o;
  o.x = f2bf(f.x); o.y = f2bf(f.y); o.z = f2bf(f.z); o.w = f2bf(f.w);
  reinterpret_cast<ushort4*>(out)[i] = o;
}

// 4 fused D*D fp32->bf16 conversions (grid.y selects matrix)
__global__ __launch_bounds__(256) void k_f2b4(
    const float* __restrict__ s0, const float* __restrict__ s1,
    const float* __restrict__ s2, const float* __restrict__ s3,
    u16* __restrict__ d0, u16* __restrict__ d1,
    u16* __restrict__ d2, u16* __restrict__ d3, int n4) {
  const float* s; u16* d;
  switch (blockIdx.y) {
    case 0: s = s0; d = d0; break;
    case 1: s = s1; d = d1; break;
    case 2: s = s2; d = d2; break;
    default: s = s3; d = d3; break;
  }
  f2b_body(s, d, blockIdx.x * 256 + threadIdx.x, n4);
}

// 2 fused DFF*D fp32->bf16 conversions (w_up, w_down)
__global__ __launch_bounds__(256) void k_f2b2(
    const float* __restrict__ s0, const float* __restrict__ s1,
    u16* __restrict__ d0, u16* __restrict__ d1, int n4) {
  const float* s = blockIdx.y ? s1 : s0;
  u16* d = blockIdx.y ? d1 : d0;
  f2b_body(s, d, blockIdx.x * 256 + threadIdx.x, n4);
}

// Permute adj fp32 [U,U] into frag-major fp16 tiles:
// adjp[(qt*16+kt)*16384 + (c16*128 + row)*8 + j] = adj[qt*128+row][kt*128+c16+16*j]
__global__ __launch_bounds__(256) void k_prep_bias(const float* __restrict__ adj,
                                                   u16* __restrict__ adjp) {
  const int tile = blockIdx.x;           // qt*16 + kt
  const int qt = tile >> 4, kt = tile & 15;
  const int t = threadIdx.x;
  const int c16 = t & 15, rblk = t >> 4; // 16 row-groups of 8
  u16* outt = adjp + (size_t)tile * 16384;
#pragma unroll
  for (int rr = 0; rr < 8; rr++) {
    int r = rblk * 8 + rr;
    const float* src = adj + (size_t)(qt * 128 + r) * U_DIM + kt * 128 + c16;
    ushort4 o0, o1;
    o0.x = f2h(src[0]);    o0.y = f2h(src[16]);  o0.z = f2h(src[32]);  o0.w = f2h(src[48]);
    o1.x = f2h(src[64]);   o1.y = f2h(src[80]);  o1.z = f2h(src[96]);  o1.w = f2h(src[112]);
    ushort4* dst = reinterpret_cast<ushort4*>(outt + ((size_t)c16 * 128 + r) * 8);
    dst[0] = o0; dst[1] = o1;
  }
}

// out4 = X4 + sum of 4 bf16 partials (+ bias[col]); fp32 out
__global__ __launch_bounds__(256) void k_reduce4(
    const u16* __restrict__ p0, const u16* __restrict__ p1,
    const u16* __restrict__ p2, const u16* __restrict__ p3,
    const float* __restrict__ X, const float* __restrict__ bias,
    float* __restrict__ out, int n4) {
  int i = blockIdx.x * 256 + threadIdx.x;
  if (i >= n4) return;
  ushort4 a = reinterpret_cast<const ushort4*>(p0)[i];
  ushort4 b = reinterpret_cast<const ushort4*>(p1)[i];
  ushort4 c = reinterpret_cast<const ushort4*>(p2)[i];
  ushort4 d = reinterpret_cast<const ushort4*>(p3)[i];
  float4 xv = reinterpret_cast<const float4*>(X)[i];
  float4 r;
  r.x = xv.x + bf2f(a.x) + bf2f(b.x) + bf2f(c.x) + bf2f(d.x);
  r.y = xv.y + bf2f(a.y) + bf2f(b.y) + bf2f(c.y) + bf2f(d.y);
  r.z = xv.z + bf2f(a.z) + bf2f(b.z) + bf2f(c.z) + bf2f(d.z);
  r.w = xv.w + bf2f(a.w) + bf2f(b.w) + bf2f(c.w) + bf2f(d.w);
  if (bias) {
    int col = (i * 4) & (D_DIM - 1);
    float4 bv = *reinterpret_cast<const float4*>(bias + col);
    r.x += bv.x; r.y += bv.y; r.z += bv.z; r.w += bv.w;
  }
  reinterpret_cast<float4*>(out)[i] = r;
}

// fused: out = X + sum(4 partials); nrm = rmsnorm(out)*w  (one block per row)
__global__ __launch_bounds__(256) void k_reduce4norm(
    const u16* __restrict__ p0, const u16* __restrict__ p1,
    const u16* __restrict__ p2, const u16* __restrict__ p3,
    const float* __restrict__ X, const float* __restrict__ w,
    float* __restrict__ out, u16* __restrict__ nrm) {
  const int row = blockIdx.x;
  const int t = threadIdx.x;
  const size_t base = (size_t)row * 512;   // float4 units per row
  float4 r[2];
  float ss = 0.f;
#pragma unroll
  for (int h = 0; h < 2; h++) {
    size_t i = base + t + h * 256;
    ushort4 a = reinterpret_cast<const ushort4*>(p0)[i];
    ushort4 b = reinterpret_cast<const ushort4*>(p1)[i];
    ushort4 c = reinterpret_cast<const ushort4*>(p2)[i];
    ushort4 d = reinterpret_cast<const ushort4*>(p3)[i];
    float4 xv = reinterpret_cast<const float4*>(X)[i];
    float4 v;
    v.x = xv.x + bf2f(a.x) + bf2f(b.x) + bf2f(c.x) + bf2f(d.x);
    v.y = xv.y + bf2f(a.y) + bf2f(b.y) + bf2f(c.y) + bf2f(d.y);
    v.z = xv.z + bf2f(a.z) + bf2f(b.z) + bf2f(c.z) + bf2f(d.z);
    v.w = xv.w + bf2f(a.w) + bf2f(b.w) + bf2f(c.w) + bf2f(d.w);
    reinterpret_cast<float4*>(out)[i] = v;
    ss += v.x*v.x + v.y*v.y + v.z*v.z + v.w*v.w;
    r[h] = v;
  }
#pragma unroll
  for (int off = 32; off > 0; off >>= 1) ss += __shfl_xor(ss, off);
  __shared__ float red[4];
  if ((t & 63) == 0) red[t >> 6] = ss;
  __syncthreads();
  float tot = red[0] + red[1] + red[2] + red[3];
  float rms = rsqrtf(tot / (float)D_DIM + EPS_RMS);
  const float4* wr = reinterpret_cast<const float4*>(w);
#pragma unroll
  for (int h = 0; h < 2; h++) {
    float4 wv = wr[t + h * 256];
    ushort4 o;
    o.x = f2bf(r[h].x * rms * wv.x); o.y = f2bf(r[h].y * rms * wv.y);
    o.z = f2bf(r[h].z * rms * wv.z); o.w = f2bf(r[h].w * rms * wv.w);
    reinterpret_cast<ushort4*>(nrm)[base + t + h * 256] = o;
  }
}

// rmsnorm: one block per row of [U_DIM, D_DIM], fp32 in -> bf16 out
__global__ __launch_bounds__(256) void k_rmsnorm(const float* __restrict__ x,
                                                 const float* __restrict__ w,
                                                 u16* __restrict__ out) {
  const int row = blockIdx.x;
  const int t = threadIdx.x;
  const float4* xr = reinterpret_cast<const float4*>(x + (size_t)row * D_DIM);
  float4 a0 = xr[t], a1 = xr[t + 256];
  float ss = a0.x*a0.x + a0.y*a0.y + a0.z*a0.z + a0.w*a0.w
           + a1.x*a1.x + a1.y*a1.y + a1.z*a1.z + a1.w*a1.w;
#pragma unroll
  for (int off = 32; off > 0; off >>= 1) ss += __shfl_xor(ss, off);
  __shared__ float red[4];
  if ((t & 63) == 0) red[t >> 6] = ss;
  __syncthreads();
  float tot = red[0] + red[1] + red[2] + red[3];
  float r = rsqrtf(tot / (float)D_DIM + EPS_RMS);
  const float4* wr = reinterpret_cast<const float4*>(w);
  float4 w0 = wr[t], w1 = wr[t + 256];
  ushort4 o0, o1;
  o0.x = f2bf(a0.x * r * w0.x); o0.y = f2bf(a0.y * r * w0.y);
  o0.z = f2bf(a0.z * r * w0.z); o0.w = f2bf(a0.w * r * w0.w);
  o1.x = f2bf(a1.x * r * w1.x); o1.y = f2bf(a1.y * r * w1.y);
  o1.z = f2bf(a1.z * r * w1.z); o1.w = f2bf(a1.w * r * w1.w);
  ushort4* op = reinterpret_cast<ushort4*>(out + (size_t)row * D_DIM);
  op[t] = o0; op[t + 256] = o1;
}

__device__ __forceinline__ void async16(u16* lds, const u16* g) {
  __builtin_amdgcn_global_load_lds(
      (__attribute__((address_space(1))) void*)(g),
      (__attribute__((address_space(3))) void*)(lds), 16, 0, 0);
}

// ====== 256x256 GEMM core, 8-wave, de-convoyed K-loop (round 9) =============
// Round-8 post-mortem: counted-vmcnt NEUTRAL -> DMA latency wasn't the limit.
// Model: per 32-K half per CU, MFMA pipe ~1240 cyc vs LDS port ~1070 cyc —
// different pipes, should overlap; measured MfmaUtil 35% says they SERIALIZE.
// Cause: per-phase s_barriers forced all 8 waves into lockstep (everyone
// ds_reads at once -> 8x port queue; everyone MFMAs at once).  Those barriers
// protected nothing (reads hit buf cur, DMA writes hit cur^1).
// New loop: ONE barrier per K-tile.  Top-of-tile: s_waitcnt vmcnt(0)
// lgkmcnt(0) (lgkm now required: with the per-phase lgkm pins gone, a wave's
// ds_reads of cur^1 must retire before it issues new DMA into cur^1) +
// sched_barrier + s_barrier + sched_barrier.  Then burst-stage tile kt+1,
// then a plain fully-unrolled 48-read/64-MFMA body with NO manual waits —
// the compiler emits fine counted lgkmcnt itself (m97) and waves skew
// freely, overlapping one wave's LDS traffic with another's MFMA (m114).
// Swizzle (round-6-verified, zero measured conflicts): slot (row,c) holds
// global chunk c ^ (row&7); stage lane l sources chunk (l&7)^(l>>3); read
// chunk (ksub*4+kq) ^ (fr&7).
#define BK64 64

__device__ __forceinline__ void gemm256_core(
    const u16* __restrict__ A, int lda,
    const u16* __restrict__ B, int ldb,
    int K, int bm, int bn, u16* smem, floatx4 acc[8][4]) {
  const int t = threadIdx.x;
  const int wv = t >> 6, lane = t & 63;
  const int wm = wv >> 2, wn = wv & 3;
  const int fr = lane & 15, kq = lane >> 4;
  const int srow = wv * 8 + (lane >> 3);
  const int scg  = (lane & 7) ^ (lane >> 3);
  const u16* Ag = A + (size_t)(bm + srow) * lda + scg * 8;
  const u16* Bg = B + (size_t)(bn + srow) * ldb + scg * 8;
  u16* AsW = smem + (wv * 8) * 64;
  u16* BsW = smem + 32768 + (wv * 8) * 64;
  const int swz  = fr & 7;
  const int arow = wm * 128 + fr;
  const int brow = wn * 64 + fr;
  const int nt = K / BK64;
  // prologue: stage tile 0 into buf 0
#pragma unroll
  for (int r = 0; r < 4; r++) async16(AsW + r * 4096, Ag + (size_t)(r * 64) * lda);
#pragma unroll
  for (int r = 0; r < 4; r++) async16(BsW + r * 4096, Bg + (size_t)(r * 64) * ldb);
  int cur = 0;
  for (int kt = 0; kt < nt; kt++) {
    asm volatile("s_waitcnt vmcnt(0) lgkmcnt(0)" ::: "memory");
    __builtin_amdgcn_sched_barrier(0);
    __builtin_amdgcn_s_barrier();
    __builtin_amdgcn_sched_barrier(0);
    asm volatile("" ::: "memory");
    if (kt + 1 < nt) {        // stage tile kt+1 into the buffer just freed
      const int nb = (cur ^ 1) * 16384;
      const size_t ko = (size_t)(kt + 1) * BK64;
#pragma unroll
      for (int r = 0; r < 4; r++) async16(AsW + nb + r * 4096, Ag + (size_t)(r * 64) * lda + ko);
#pragma unroll
      for (int r = 0; r < 4; r++) async16(BsW + nb + r * 4096, Bg + (size_t)(r * 64) * ldb + ko);
    }
    const u16* Ab = smem + cur * 16384;
    const u16* Bb = smem + 32768 + cur * 16384;
    // free-form tile body: no barriers, no manual waits — compiler schedules,
    // waves skew, LDS and MFMA pipes overlap across waves.
#pragma unroll
    for (int ksub = 0; ksub < 2; ksub++) {
      const int cswz = (((ksub * 4 + kq) ^ swz) * 8);
      shortx8 bfr[4];
#pragma unroll
      for (int j = 0; j < 4; j++)
        bfr[j] = *reinterpret_cast<const shortx8*>(Bb + (brow + j * 16) * 64 + cswz);
#pragma unroll
      for (int mi = 0; mi < 8; mi++) {
        shortx8 afr = *reinterpret_cast<const shortx8*>(Ab + (arow + mi * 16) * 64 + cswz);
#pragma unroll
        for (int j = 0; j < 4; j++)
          acc[mi][j] = __builtin_amdgcn_mfma_f32_16x16x32_bf16(afr, bfr[j], acc[mi][j], 0, 0, 0);
      }
    }
    cur ^= 1;
  }
}

#define GEMM256_PRELUDE                                           \
  __shared__ u16 smem[65536]; /* 128 KB */                        \
  floatx4 acc[8][4];                                              \
  {                                                               \
    floatx4 zf = {0.f, 0.f, 0.f, 0.f};                            \
    for (int i = 0; i < 8; i++)                                   \
      for (int j = 0; j < 4; j++) acc[i][j] = zf;                 \
  }                                                               \
  const int bm = blockIdx.y * 256, bn = blockIdx.x * 256;

#define EPILOG256                                                 \
  const int lane_ = threadIdx.x & 63;                             \
  const int wv_ = threadIdx.x >> 6;                               \
  const int fr_ = lane_ & 15, kq_ = lane_ >> 4;                   \
  const int row0 = (wv_ >> 2) * 128 + kq_ * 4;                    \
  const int col0 = (wv_ & 3) * 64 + fr_;

__global__ __launch_bounds__(512, 1) void k_gemm_qkv(
    const u16* __restrict__ A, const u16* __restrict__ B,
    u16* __restrict__ Q, u16* __restrict__ Ko, u16* __restrict__ VT) {
  GEMM256_PRELUDE;
  gemm256_core(A, D_DIM, B, D_DIM, D_DIM, bm, bn, smem, acc);
  EPILOG256;
  if (bn < 4096) {
    u16* C = (bn < 2048) ? Q : Ko;
    const int cb = (bn < 2048) ? bn : bn - 2048;
#pragma unroll
    for (int mt = 0; mt < 8; mt++)
#pragma unroll
      for (int i = 0; i < 4; i++) {
        u16* cr = C + (size_t)(bm + row0 + mt*16 + i) * D_DIM + cb + col0;
#pragma unroll
        for (int nt = 0; nt < 4; nt++) cr[nt*16] = f2bf(acc[mt][nt][i]);
      }
  } else {
    const int cb = bn - 4096;
#pragma unroll
    for (int mt = 0; mt < 8; mt++)
#pragma unroll
      for (int nt = 0; nt < 4; nt++) {
        int col = cb + col0 + nt*16;
        int row = bm + row0 + mt*16;
        ushort4 o;
        o.x = f2bf(acc[mt][nt][0]); o.y = f2bf(acc[mt][nt][1]);
        o.z = f2bf(acc[mt][nt][2]); o.w = f2bf(acc[mt][nt][3]);
        *reinterpret_cast<ushort4*>(VT + (size_t)col * U_DIM + row) = o;
      }
  }
}

__global__ __launch_bounds__(512, 1) void k_gemm_splitk_part(
    const u16* __restrict__ A, int lda, const u16* __restrict__ B, int ldb,
    int Kc, u16* __restrict__ P, size_t pstride, int ldc) {
  GEMM256_PRELUDE;
  const int koff = blockIdx.z * Kc;
  gemm256_core(A + koff, lda, B + koff, ldb, Kc, bm, bn, smem, acc);
  u16* Pz = P + (size_t)blockIdx.z * pstride;
  EPILOG256;
#pragma unroll
  for (int mt = 0; mt < 8; mt++)
#pragma unroll
    for (int i = 0; i < 4; i++) {
      u16* cr = Pz + (size_t)(bm + row0 + mt*16 + i) * ldc + bn + col0;
#pragma unroll
      for (int nt = 0; nt < 4; nt++) cr[nt*16] = f2bf(acc[mt][nt][i]);
    }
}

__device__ __forceinline__ float fast_gelu(float v) {
  float u = v * (0.79788456080286536f + 0.035677408136300125f * v * v);
  float tt = fminf(fmaxf(2.f * u, -40.f), 40.f);
  float e = __expf(tt);
  return 0.5f * v * (1.f + (e - 1.f) / (e + 1.f));
}

__global__ __launch_bounds__(512, 1) void k_gemm_gelu(
    const u16* __restrict__ A, int lda, const u16* __restrict__ B, int ldb,
    int K, const float* __restrict__ bias, u16* __restrict__ C, int ldc) {
  GEMM256_PRELUDE;
  gemm256_core(A, lda, B, ldb, K, bm, bn, smem, acc);
  EPILOG256;
#pragma unroll
  for (int mt = 0; mt < 8; mt++)
#pragma unroll
    for (int i = 0; i < 4; i++) {
      size_t off = (size_t)(bm + row0 + mt*16 + i) * ldc + bn + col0;
#pragma unroll
      for (int nt = 0; nt < 4; nt++) {
        float v = acc[mt][nt][i] + bias[bn + col0 + nt*16];
        C[off + nt*16] = f2bf(fast_gelu(v));
      }
    }
}

// ---------------- Flash attention, KVBLK=64 (verified round 7) --------------
__global__ __launch_bounds__(256) void k_flash(
    const u16* __restrict__ Q, const u16* __restrict__ K,
    const u16* __restrict__ VT, const u16* __restrict__ ADJP,
    u16* __restrict__ O) {
  __shared__ u16 smem[36864];  // 72 KB
  const int qt = blockIdx.x, gh = blockIdx.y;   // qt in [0,32)
  const int t = threadIdx.x, wv = t >> 6, lane = t & 63;
  const int fr = lane & 15, kq = lane >> 4;
  const int c4 = lane & 3, r4 = lane >> 2;

  const u16* gq = Q + (size_t)(qt * 64) * D_DIM + gh * DH;
  const u16* gk = K + gh * DH;
  const u16* gv = VT + (size_t)(gh * DH) * U_DIM;

  // stage Q [64][128] rot16 into smem[0..8192)
#pragma unroll
  for (int it = 0; it < 4; it++) {
    int row = wv * 16 + it * 4 + kq;
    int cg = (fr + row) & 15;
    async16(smem + row * 128 + fr * 8, gq + (size_t)row * D_DIM + cg * 8);
  }
  __builtin_amdgcn_s_waitcnt(0);
  __syncthreads();
  shortx8 qf[4];
#pragma unroll
  for (int ks = 0; ks < 4; ks++) {
    int row = wv * 16 + fr;
    int slot = ((ks * 4 + kq) - row) & 15;
    qf[ks] = *reinterpret_cast<const shortx8*>(smem + row * 128 + slot * 8);
  }
  __syncthreads();  // Q reads done; smem reusable

  floatx4 oacc[8];
  float lrow[4];
#pragma unroll
  for (int nt = 0; nt < 8; nt++) { floatx4 z = {0.f,0.f,0.f,0.f}; oacc[nt] = z; }
#pragma unroll
  for (int i = 0; i < 4; i++) lrow[i] = 0.f;

  // stage K/V 64-key tile 0 into buffer 0
  {
    u16* Ks = smem; u16* Vs = smem + 16384;
#pragma unroll
    for (int it = 0; it < 4; it++) {            // K: 64 rows rot16
      int row = wv * 16 + it * 4 + kq;
      int cg = (fr + row) & 15;
      async16(Ks + row * 128 + fr * 8, gk + (size_t)row * D_DIM + cg * 8);
    }
#pragma unroll
    for (int sub = 0; sub < 2; sub++)           // V: 2 sub-blocks [128][32]
#pragma unroll
      for (int it = 0; it < 2; it++) {
        int row = wv * 32 + it * 16 + r4;
        int cg = (c4 + (row >> 1)) & 3;
        async16(Vs + sub * 4096 + row * 32 + c4 * 8,
                gv + (size_t)row * U_DIM + sub * 32 + cg * 8);
      }
  }

  u16* Pb = smem + 32768;
  for (int kt64 = 0; kt64 < 32; kt64++) {
    const int cur = kt64 & 1;
    u16* Ks = smem + cur * 8192;
    u16* Vs = smem + 16384 + cur * 8192;
    asm volatile("s_waitcnt vmcnt(0)" ::: "memory");
    __builtin_amdgcn_s_barrier();        // B1: buf[cur] DMA complete everywhere
    asm volatile("" ::: "memory");
    if (kt64 < 31) {   // prefetch buf[1-cur]; stays in flight to next B1
      u16* Kn = smem + (1 - cur) * 8192;
      u16* Vn = smem + 16384 + (1 - cur) * 8192;
      const u16* gkn = gk + (size_t)((kt64 + 1) * 64) * D_DIM;
      const u16* gvn = gv + (kt64 + 1) * 64;
#pragma unroll
      for (int it = 0; it < 4; it++) {
        int row = wv * 16 + it * 4 + kq;
        int cg = (fr + row) & 15;
        async16(Kn + row * 128 + fr * 8, gkn + (size_t)row * D_DIM + cg * 8);
      }
#pragma unroll
      for (int sub = 0; sub < 2; sub++)
#pragma unroll
        for (int it = 0; it < 2; it++) {
          int row = wv * 32 + it * 16 + r4;
          int cg = (c4 + (row >> 1)) & 3;
          async16(Vn + sub * 4096 + row * 32 + c4 * 8,
                  gvn + (size_t)row * U_DIM + sub * 32 + cg * 8);
        }
    }

    // S = Q K^T (64 keys -> 4 column groups: fr, 16+fr, 32+fr, 48+fr)
    floatx4 sacc[4];
    { floatx4 z = {0.f,0.f,0.f,0.f}; sacc[0]=z; sacc[1]=z; sacc[2]=z; sacc[3]=z; }
#pragma unroll
    for (int ks = 0; ks < 4; ks++) {
      int slotA = ((ks * 4 + kq) - fr) & 15;
      int slotB = ((ks * 4 + kq) - (16 + fr)) & 15;
      shortx8 kf0 = *reinterpret_cast<const shortx8*>(Ks + fr * 128 + slotA * 8);
      shortx8 kf1 = *reinterpret_cast<const shortx8*>(Ks + (16 + fr) * 128 + slotB * 8);
      shortx8 kf2 = *reinterpret_cast<const shortx8*>(Ks + (32 + fr) * 128 + slotA * 8);
      shortx8 kf3 = *reinterpret_cast<const shortx8*>(Ks + (48 + fr) * 128 + slotB * 8);
      sacc[0] = __builtin_amdgcn_mfma_f32_16x16x32_bf16(qf[ks], kf0, sacc[0], 0, 0, 0);
      sacc[1] = __builtin_amdgcn_mfma_f32_16x16x32_bf16(qf[ks], kf1, sacc[1], 0, 0, 0);
      sacc[2] = __builtin_amdgcn_mfma_f32_16x16x32_bf16(qf[ks], kf2, sacc[2], 0, 0, 0);
      sacc[3] = __builtin_amdgcn_mfma_f32_16x16x32_bf16(qf[ks], kf3, sacc[3], 0, 0, 0);
    }

    // fixed-shift softmax numerators; Pb row stride 64, sub-block = col>>5
    const u16* bt = ADJP + ((size_t)(qt >> 1) * 16 + (kt64 >> 1)) * 16384 + (kt64 & 1) * 4;
#pragma unroll
    for (int i = 0; i < 4; i++) {
      int rl = wv * 16 + kq * 4 + i;
      int r128 = (qt & 1) * 64 + rl;
      ushort4 bh = *reinterpret_cast<const ushort4*>(bt + ((size_t)fr * 128 + r128) * 8);
      float s0 = sacc[0][i] * ATTN_SCALE + h2f(bh.x);
      float s1 = sacc[1][i] * ATTN_SCALE + h2f(bh.y);
      float s2 = sacc[2][i] * ATTN_SCALE + h2f(bh.z);
      float s3 = sacc[3][i] * ATTN_SCALE + h2f(bh.w);
      float p0 = __expf(fminf(s0, 80.f));
      float p1 = __expf(fminf(s1, 80.f));
      float p2 = __expf(fminf(s2, 80.f));
      float p3 = __expf(fminf(s3, 80.f));
      int slot0 = ((fr >> 3) - (rl >> 1)) & 3;
      int slot1 = (((16 + fr) >> 3) - (rl >> 1)) & 3;
      Pb[rl * 64 + slot0 * 8 + (fr & 7)] = f2bf(p0);
      Pb[rl * 64 + slot1 * 8 + (fr & 7)] = f2bf(p1);
      Pb[rl * 64 + 32 + slot0 * 8 + (fr & 7)] = f2bf(p2);
      Pb[rl * 64 + 32 + slot1 * 8 + (fr & 7)] = f2bf(p3);
      lrow[i] += (p0 + p1) + (p2 + p3);
    }
    asm volatile("s_waitcnt lgkmcnt(0)" ::: "memory");
    __builtin_amdgcn_s_barrier();        // B2: Pb visible; prefetch in flight
    asm volatile("" ::: "memory");

    // O += P V   (k = 64 -> two MFMA k-steps per nt)
    shortx8 pf0, pf1;
    {
      int row = wv * 16 + fr;
      int slot = (kq - (row >> 1)) & 3;
      pf0 = *reinterpret_cast<const shortx8*>(Pb + row * 64 + slot * 8);
      pf1 = *reinterpret_cast<const shortx8*>(Pb + row * 64 + 32 + slot * 8);
    }
#pragma unroll
    for (int nt = 0; nt < 8; nt++) {
      int row = nt * 16 + fr;
      int slot = (kq - (row >> 1)) & 3;
      shortx8 vf0 = *reinterpret_cast<const shortx8*>(Vs + row * 32 + slot * 8);
      shortx8 vf1 = *reinterpret_cast<const shortx8*>(Vs + 4096 + row * 32 + slot * 8);
      oacc[nt] = __builtin_amdgcn_mfma_f32_16x16x32_bf16(pf0, vf0, oacc[nt], 0, 0, 0);
      oacc[nt] = __builtin_amdgcn_mfma_f32_16x16x32_bf16(pf1, vf1, oacc[nt], 0, 0, 0);
    }
    // (next-iter B1 orders Pb/Vs reads vs writes)
  }

  // epilogue: one cross-lane l-reduce per row, normalize, store bf16
#pragma unroll
  for (int i = 0; i < 4; i++) {
    int rl = wv * 16 + kq * 4 + i;
    float l = lrow[i];
    l += __shfl_xor(l, 1);
    l += __shfl_xor(l, 2);
    l += __shfl_xor(l, 4);
    l += __shfl_xor(l, 8);
    float inv = 1.f / l;
    u16* orow = O + (size_t)(qt * 64 + rl) * D_DIM + gh * DH + fr;
#pragma unroll
    for (int nt = 0; nt < 8; nt++)
      orow[nt * 16] = f2bf(oacc[nt][i] * inv);
  }
}

// Workspace timeline (MB offsets, peak 104):
//  A: hb@0-8, wob@48-56, wqkv@56-80, adjp@32-40 (prep)
//  B: qkv -> qb@8-16 kb@16-24 vtb@24-32
//  C: flash -> aob@40-48  (reads qb,kb,vtb,adjp)
//  D: out-proj partials opp@8-40 (qb/kb/vtb/adjp dead); reduce4norm -> out, h2b
//  E: wub@8-40 (opp dead), wdb@72-104 (wqkv dead) [one fused f2b2 launch];
//     ffb@40-72 (aob/wob dead); down partials dpp@8-40 (wub dead after gelu);
//     reduce -> out += sum + b_down
extern "C" void kernel_launch(void* const* d_in, const int* in_sizes, int n_in,
                              void* d_out, int out_size, void* d_ws, size_t ws_size,
                              hipStream_t stream) {
  (void)in_sizes; (void)n_in; (void)out_size; (void)ws_size;
  const float* x      = (const float*)d_in[0];
  const float* adj    = (const float*)d_in[1];
  const float* n1w    = (const float*)d_in[2];
  const float* n2w    = (const float*)d_in[3];
  const float* wq     = (const float*)d_in[4];
  const float* wk     = (const float*)d_in[5];
  const float* wv     = (const float*)d_in[6];
  const float* wo     = (const float*)d_in[7];
  const float* w_up   = (const float*)d_in[8];
  const float* b_up   = (const float*)d_in[9];
  const float* w_down = (const float*)d_in[10];
  const float* b_down = (const float*)d_in[11];
  float* out = (float*)d_out;
  char* ws = (char*)d_ws;
  const size_t MB = 1u << 20;
  u16* hb   = (u16*)(ws + 0*MB);
  u16* qb   = (u16*)(ws + 8*MB);
  u16* kb   = (u16*)(ws + 16*MB);
  u16* vtb  = (u16*)(ws + 24*MB);
  u16* adjp = (u16*)(ws + 32*MB);
  u16* aob  = (u16*)(ws + 40*MB);
  u16* wob  = (u16*)(ws + 48*MB);
  u16* wqkv = (u16*)(ws + 56*MB);
  u16* opp  = (u16*)(ws + 8*MB);   // 4 x 8MB out-proj partials
  u16* h2b  = (u16*)(ws + 0*MB);
  u16* wub  = (u16*)(ws + 8*MB);
  u16* ffb  = (u16*)(ws + 40*MB);
  u16* wdb  = (u16*)(ws + 72*MB);
  u16* dpp  = (u16*)(ws + 8*MB);   // 4 x 8MB FFN-down partials (overlays wub)

  dim3 blk(256);
  dim3 blk512(512);
  const int n4d = (D_DIM * D_DIM) / 4;
  const int n4f = (DFF * D_DIM) / 4;
  const size_t szd = (size_t)D_DIM * D_DIM;

  // phase A: fused weight conversion + bias permute + norm1
  k_f2b4<<<dim3((n4d + 255) / 256, 4), blk, 0, stream>>>(
      wq, wk, wv, wo, wqkv, wqkv + szd, wqkv + 2*szd, wob, n4d);
  k_prep_bias<<<256, blk, 0, stream>>>(adj, adjp);
  k_rmsnorm<<<U_DIM, blk, 0, stream>>>(x, n1w, hb);

  // phase B: fused QKV (256^2 tiles: 24 x 8 = 192 blocks)
  k_gemm_qkv<<<dim3(24, 8), blk512, 0, stream>>>(hb, wqkv, qb, kb, vtb);

  // phase C: flash attention (512 blocks, KVBLK=64) -> aob
  k_flash<<<dim3(32, 16), blk, 0, stream>>>(qb, kb, vtb, adjp, aob);

  // phase D: out-projection split-K4; fused reduce+residual+rmsnorm2
  k_gemm_splitk_part<<<dim3(8, 8, 4), blk512, 0, stream>>>(
      aob, D_DIM, wob, D_DIM, D_DIM/4, opp, szd, D_DIM);
  k_reduce4norm<<<U_DIM, blk, 0, stream>>>(
      opp, opp + szd, opp + 2*szd, opp + 3*szd, x, n2w, out, h2b);

  // phase E: FFN (fused w_up+w_down conversion in one launch)
  k_f2b2<<<dim3((n4f + 255) / 256, 2), blk, 0, stream>>>(w_up, w_down, wub, wdb, n4f);
  k_gemm_gelu<<<dim3(32, 8), blk512, 0, stream>>>(h2b, D_DIM, wub, D_DIM, D_DIM,
                                                  b_up, ffb, DFF);
  k_gemm_splitk_part<<<dim3(8, 8, 4), blk512, 0, stream>>>(
      ffb, DFF, wdb, DFF, DFF/4, dpp, szd, D_DIM);
  k_reduce4<<<(n4d + 255) / 256, blk, 0, stream>>>(
      dpp, dpp + szd, dpp + 2*szd, dpp + 3*szd, out, b_down, out, n4d);
}